// Round 1
// baseline (205.312 us; speedup 1.0000x reference)
//
#include <hip/hip_runtime.h>
#include <hip/hip_bf16.h>

// HierarchicalEmbedding: per-token embedding gather + weighted digit accumulation.
//
// out[n, :] = mods[n]==2 ? E1[fidx]*vals[n]
//                        : E1[fidx] + sum_{i<ndigits[n]} (1/(i+2)^kappa) * Eint[digits[n,i]]
// fidx = mods==0 ? fc+5 : mods==1 ? 2*fc+5 : 52+fc
//
// Memory-bound: ~128 MB output write dominates. One thread per float4 (32
// threads per token), grid-stride loop.

#define LM1 6
#define D   128

__global__ __launch_bounds__(256) void hier_emb_kernel(
    const int*   __restrict__ first_chars,
    const int*   __restrict__ digits,
    const int*   __restrict__ ndigits,
    const int*   __restrict__ mods,
    const float* __restrict__ vals,
    const float* __restrict__ E1,
    const float* __restrict__ Eint,
    const int*   __restrict__ kappa_p,
    float*       __restrict__ out,
    int n)
{
    const int k = *kappa_p;

    // Precompute the 6 position weights (uniform across threads; cheap VALU).
    float w[LM1];
#pragma unroll
    for (int i = 0; i < LM1; ++i) {
        float p = 1.0f;
        const float b = (float)(i + 2);
        for (int j = 0; j < k; ++j) p *= b;
        w[i] = 1.0f / p;
    }

    const long total = (long)n * 32;   // one work item per float4 of output
    const long stride = (long)gridDim.x * blockDim.x;

    for (long gid = (long)blockIdx.x * blockDim.x + threadIdx.x;
         gid < total; gid += stride) {
        const int tok = (int)(gid >> 5);
        const int q   = (int)(gid & 31);       // float4 index within the D=128 row

        const int mod = mods[tok];
        const int fc  = first_chars[tok];
        const int fidx = (mod == 0) ? (fc + 5)
                       : (mod == 1) ? (fc * 2 + 5)
                                    : (52 + fc);

        const float4 base =
            *reinterpret_cast<const float4*>(E1 + (size_t)fidx * D + q * 4);

        float4 acc;
        if (mod == 2) {
            const float v = vals[tok];
            acc.x = base.x * v; acc.y = base.y * v;
            acc.z = base.z * v; acc.w = base.w * v;
        } else {
            acc = base;
            const int nd = ndigits[tok];
#pragma unroll
            for (int i = 0; i < LM1; ++i) {
                if (i < nd) {
                    const int dg = digits[tok * LM1 + i];
                    const float4 e =
                        *reinterpret_cast<const float4*>(Eint + dg * D + q * 4);
                    acc.x += w[i] * e.x; acc.y += w[i] * e.y;
                    acc.z += w[i] * e.z; acc.w += w[i] * e.w;
                }
            }
        }

        *reinterpret_cast<float4*>(out + ((size_t)tok * D) + q * 4) = acc;
    }
}

extern "C" void kernel_launch(void* const* d_in, const int* in_sizes, int n_in,
                              void* d_out, int out_size, void* d_ws, size_t ws_size,
                              hipStream_t stream) {
    const int*   first_chars = (const int*)  d_in[0];
    const int*   digits      = (const int*)  d_in[1];
    const int*   ndigits     = (const int*)  d_in[2];
    const int*   mods        = (const int*)  d_in[3];
    const float* vals        = (const float*)d_in[4];
    const float* E1          = (const float*)d_in[5];
    const float* Eint        = (const float*)d_in[6];
    const int*   kappa       = (const int*)  d_in[7];
    float*       out         = (float*)d_out;

    const int n = in_sizes[0];          // number of tokens
    const long total = (long)n * 32;    // float4 work items
    const int block = 256;
    long grid_l = (total + block - 1) / block;
    if (grid_l > 4096) grid_l = 4096;   // grid-stride the rest
    const int grid = (int)grid_l;

    hier_emb_kernel<<<grid, block, 0, stream>>>(
        first_chars, digits, ndigits, mods, vals, E1, Eint, kappa, out, n);
}

// Round 2
// 186.922 us; speedup vs baseline: 1.0984x; 1.0984x over previous
//
#include <hip/hip_runtime.h>
#include <hip/hip_bf16.h>

// HierarchicalEmbedding: per-token embedding gather + weighted digit accumulation.
//
// out[n, :] = mods[n]==2 ? E1[fidx]*vals[n]
//                        : E1[fidx] + sum_{i<ndigits[n]} (1/(i+2)^kappa) * Eint[digits[n,i]]
// fidx = mods==0 ? fc+5 : mods==1 ? 2*fc+5 : 52+fc
//
// Latency-bound fix (R2): 4 tokens per thread at one float4 slot, phase-split
// loads for max memory-level parallelism. No grid-stride loop.

#define LM1 6
#define D   128
#define TPT 4   // tokens per thread

__global__ __launch_bounds__(256) void hier_emb_kernel(
    const int*   __restrict__ first_chars,
    const int*   __restrict__ digits,
    const int*   __restrict__ ndigits,
    const int*   __restrict__ mods,
    const float* __restrict__ vals,
    const float* __restrict__ E1,
    const float* __restrict__ Eint,
    const int*   __restrict__ kappa_p,
    float*       __restrict__ out,
    int n)
{
    const int k = *kappa_p;

    // Position weights 1/(i+2)^kappa (uniform; cheap VALU).
    float w[LM1];
#pragma unroll
    for (int i = 0; i < LM1; ++i) {
        float p = 1.0f;
        const float b = (float)(i + 2);
        for (int j = 0; j < k; ++j) p *= b;
        w[i] = 1.0f / p;
    }

    const long u = (long)blockIdx.x * blockDim.x + threadIdx.x;
    const int q  = (int)(u & 31);              // float4 slot within the row
    const int tb = (int)(u >> 5) * TPT;        // first token of this thread's group
    if (tb >= n) return;

    // Clamped token indices (avoid OOB loads on the tail; stores are guarded).
    int t[TPT];
#pragma unroll
    for (int j = 0; j < TPT; ++j) {
        int tt = tb + j;
        t[j] = tt < n ? tt : (n - 1);
    }

    // Phase 1: per-token scalars (independent loads).
    int mod[TPT], fc[TPT], nd[TPT];
    float vv[TPT];
#pragma unroll
    for (int j = 0; j < TPT; ++j) mod[j] = mods[t[j]];
#pragma unroll
    for (int j = 0; j < TPT; ++j) fc[j] = first_chars[t[j]];
#pragma unroll
    for (int j = 0; j < TPT; ++j) nd[j] = ndigits[t[j]];
#pragma unroll
    for (int j = 0; j < TPT; ++j) vv[j] = vals[t[j]];

    // Phase 2: digit indices (unconditional — always valid memory).
    int dg[TPT][LM1];
#pragma unroll
    for (int j = 0; j < TPT; ++j) {
#pragma unroll
        for (int i = 0; i < LM1; ++i) dg[j][i] = digits[t[j] * LM1 + i];
    }

    // Phase 3: E1 gathers (4 independent 16B loads, L2-resident table).
    float4 base[TPT];
#pragma unroll
    for (int j = 0; j < TPT; ++j) {
        const int fidx = (mod[j] == 0) ? (fc[j] + 5)
                       : (mod[j] == 1) ? (fc[j] * 2 + 5)
                                       : (52 + fc[j]);
        base[j] = *reinterpret_cast<const float4*>(E1 + (size_t)fidx * D + q * 4);
    }

    // Phase 4: accumulate (Eint is 5KB, L1-resident).
    float4 acc[TPT];
#pragma unroll
    for (int j = 0; j < TPT; ++j) {
        if (mod[j] == 2) {
            const float v = vv[j];
            acc[j].x = base[j].x * v; acc[j].y = base[j].y * v;
            acc[j].z = base[j].z * v; acc[j].w = base[j].w * v;
        } else {
            acc[j] = base[j];
#pragma unroll
            for (int i = 0; i < LM1; ++i) {
                if (i < nd[j]) {
                    const float4 e = *reinterpret_cast<const float4*>(
                        Eint + dg[j][i] * D + q * 4);
                    acc[j].x += w[i] * e.x; acc[j].y += w[i] * e.y;
                    acc[j].z += w[i] * e.z; acc[j].w += w[i] * e.w;
                }
            }
        }
    }

    // Phase 5: coalesced stores (each j: 32 lanes cover one 512B row).
#pragma unroll
    for (int j = 0; j < TPT; ++j) {
        if (tb + j < n) {
            *reinterpret_cast<float4*>(out + (size_t)(tb + j) * D + q * 4) = acc[j];
        }
    }
}

extern "C" void kernel_launch(void* const* d_in, const int* in_sizes, int n_in,
                              void* d_out, int out_size, void* d_ws, size_t ws_size,
                              hipStream_t stream) {
    const int*   first_chars = (const int*)  d_in[0];
    const int*   digits      = (const int*)  d_in[1];
    const int*   ndigits     = (const int*)  d_in[2];
    const int*   mods        = (const int*)  d_in[3];
    const float* vals        = (const float*)d_in[4];
    const float* E1          = (const float*)d_in[5];
    const float* Eint        = (const float*)d_in[6];
    const int*   kappa       = (const int*)  d_in[7];
    float*       out         = (float*)d_out;

    const int n = in_sizes[0];                         // tokens
    const long threads = ((long)(n + TPT - 1) / TPT) * 32;
    const int block = 256;
    const int grid = (int)((threads + block - 1) / block);

    hier_emb_kernel<<<grid, block, 0, stream>>>(
        first_chars, digits, ndigits, mods, vals, E1, Eint, kappa, out, n);
}

// Round 5
// 166.520 us; speedup vs baseline: 1.2330x; 1.1225x over previous
//
#include <hip/hip_runtime.h>
#include <hip/hip_bf16.h>

// HierarchicalEmbedding: per-token embedding gather + weighted digit accumulation.
//
// out[n, :] = mods[n]==2 ? E1[fidx]*vals[n]
//                        : E1[fidx] + sum_{i<ndigits[n]} (1/(i+2)^kappa) * Eint[digits[n,i]]
// fidx = mods==0 ? fc+5 : mods==1 ? 2*fc+5 : 52+fc
//
// R5 == R3 resubmit (two infra failures). VMEM-instruction bound fix:
// stage Eint (5KB) + per-token metadata in LDS (coalesced, once per block).
// Global VMEM per thread: 4 E1 gathers + 4 stores + ~2 staging loads
// (was ~60 incl. 28 redundant scalar loads).

#define LM1 6
#define D   128
#define TPB 32   // tokens per block
#define TPT 4    // tokens per thread (8 lane-groups of 32 * TPT = TPB)

__global__ __launch_bounds__(256) void hier_emb_kernel(
    const int*   __restrict__ first_chars,
    const int*   __restrict__ digits,
    const int*   __restrict__ ndigits,
    const int*   __restrict__ mods,
    const float* __restrict__ vals,
    const float* __restrict__ E1,
    const float* __restrict__ Eint,
    const int*   __restrict__ kappa_p,
    float*       __restrict__ out,
    int n)
{
    __shared__ float sEint[10][D];       // 5 KB, digit embedding table
    __shared__ int   sFidx[TPB];
    __shared__ int   sNd[TPB];
    __shared__ int   sMod[TPB];
    __shared__ float sVal[TPB];
    __shared__ int   sDig[TPB * LM1];    // 768 B, linear for coalesced staging

    const int tid  = threadIdx.x;
    const int tok0 = blockIdx.x * TPB;

    // --- Stage Eint: 1280 floats = 320 float4; 256 threads -> 2 each (64 idle 2nd) ---
    {
        const float4* src = reinterpret_cast<const float4*>(Eint);
        float4*       dst = reinterpret_cast<float4*>(&sEint[0][0]);
        dst[tid] = src[tid];                       // 0..255
        const int i2 = 256 + tid;
        if (i2 < (10 * D) / 4) dst[i2] = src[i2]; // 256..319
    }

    // --- Stage per-token metadata (coalesced) ---
    if (tid < TPB) {
        int tt = tok0 + tid; if (tt >= n) tt = n - 1;
        const int mod = mods[tt];
        const int fc  = first_chars[tt];
        sMod[tid]  = mod;
        sFidx[tid] = (mod == 0) ? (fc + 5) : (mod == 1) ? (fc * 2 + 5) : (52 + fc);
        sNd[tid]   = ndigits[tt];
        sVal[tid]  = vals[tt];
    } else if (tid >= 64) {
        // threads 64..255 load the 192 digit ints for this block, coalesced
        const int i = tid - 64;                     // 0..191
        long gi = (long)tok0 * LM1 + i;
        const long lim = (long)n * LM1;
        if (gi >= lim) gi = lim - 1;
        sDig[i] = digits[gi];
    }

    // Position weights 1/(i+2)^kappa (uniform; tiny VALU).
    const int k = *kappa_p;
    float w[LM1];
#pragma unroll
    for (int i = 0; i < LM1; ++i) {
        float p = 1.0f;
        const float b = (float)(i + 2);
        for (int j = 0; j < k; ++j) p *= b;
        w[i] = 1.0f / p;
    }

    __syncthreads();

    const int q   = tid & 31;             // float4 slot within the D=128 row
    const int ltb = (tid >> 5) * TPT;     // first local token of this thread

    // --- Phase: 4 independent E1 gathers (L2-resident table) ---
    float4 base[TPT];
#pragma unroll
    for (int j = 0; j < TPT; ++j) {
        const int fidx = sFidx[ltb + j];  // LDS broadcast across lanes 0-31
        base[j] = *reinterpret_cast<const float4*>(E1 + (size_t)fidx * D + q * 4);
    }

    // --- Accumulate digit embeddings from LDS ---
    float4 acc[TPT];
#pragma unroll
    for (int j = 0; j < TPT; ++j) {
        const int lt  = ltb + j;
        const int mod = sMod[lt];
        if (mod == 2) {
            const float v = sVal[lt];
            acc[j].x = base[j].x * v; acc[j].y = base[j].y * v;
            acc[j].z = base[j].z * v; acc[j].w = base[j].w * v;
        } else {
            acc[j] = base[j];
            const int nd = sNd[lt];
#pragma unroll
            for (int i = 0; i < LM1; ++i) {
                if (i < nd) {             // uniform across the 32 lanes of a token
                    const int dg = sDig[lt * LM1 + i];
                    const float4 e =
                        *reinterpret_cast<const float4*>(&sEint[dg][q * 4]);
                    acc[j].x += w[i] * e.x; acc[j].y += w[i] * e.y;
                    acc[j].z += w[i] * e.z; acc[j].w += w[i] * e.w;
                }
            }
        }
    }

    // --- Coalesced stores: each j, lanes 0-31 cover one 512B row ---
#pragma unroll
    for (int j = 0; j < TPT; ++j) {
        const int tok = tok0 + ltb + j;
        if (tok < n) {
            *reinterpret_cast<float4*>(out + (size_t)tok * D + q * 4) = acc[j];
        }
    }
}

extern "C" void kernel_launch(void* const* d_in, const int* in_sizes, int n_in,
                              void* d_out, int out_size, void* d_ws, size_t ws_size,
                              hipStream_t stream) {
    const int*   first_chars = (const int*)  d_in[0];
    const int*   digits      = (const int*)  d_in[1];
    const int*   ndigits     = (const int*)  d_in[2];
    const int*   mods        = (const int*)  d_in[3];
    const float* vals        = (const float*)d_in[4];
    const float* E1          = (const float*)d_in[5];
    const float* Eint        = (const float*)d_in[6];
    const int*   kappa       = (const int*)  d_in[7];
    float*       out         = (float*)d_out;

    const int n    = in_sizes[0];                 // tokens
    const int grid = (n + TPB - 1) / TPB;         // 8192 blocks at N=262144

    hier_emb_kernel<<<grid, 256, 0, stream>>>(
        first_chars, digits, ndigits, mods, vals, E1, Eint, kappa, out, n);
}

// Round 7
// 165.429 us; speedup vs baseline: 1.2411x; 1.0066x over previous
//
#include <hip/hip_runtime.h>
#include <hip/hip_bf16.h>

// HierarchicalEmbedding: per-token embedding gather + weighted digit accumulation.
//
// out[n, :] = mods[n]==2 ? E1[fidx]*vals[n]
//                        : E1[fidx] + sum_{i<ndigits[n]} (1/(i+2)^kappa) * Eint[digits[n,i]]
// fidx = mods==0 ? fc+5 : mods==1 ? 2*fc+5 : 52+fc
//
// R7 == R6 with the nontemporal-store type fixed (clang ext_vector float4;
// HIP_vector_type is rejected by __builtin_nontemporal_store).
// TPB 128 (grid 2048): Eint+metadata staged once per block, 4 chunks of 32
// tokens. Nontemporal stores keep the 128MB write stream out of L2.

#define LM1 6
#define D   128
#define TPB 128  // tokens per block
#define TPT 4    // tokens per thread per chunk
#define NCHUNK (TPB / 32)   // 4 chunks of 32 tokens

typedef float nfloat4 __attribute__((ext_vector_type(4)));  // native vec for builtins

__global__ __launch_bounds__(256) void hier_emb_kernel(
    const int*   __restrict__ first_chars,
    const int*   __restrict__ digits,
    const int*   __restrict__ ndigits,
    const int*   __restrict__ mods,
    const float* __restrict__ vals,
    const float* __restrict__ E1,
    const float* __restrict__ Eint,
    const int*   __restrict__ kappa_p,
    float*       __restrict__ out,
    int n)
{
    __shared__ float sEint[10][D];       // 5 KB, digit embedding table
    __shared__ int   sFidx[TPB];
    __shared__ int   sNd[TPB];
    __shared__ int   sMod[TPB];
    __shared__ float sVal[TPB];
    __shared__ int   sDig[TPB * LM1];    // 3 KB, linear for coalesced staging

    const int tid  = threadIdx.x;
    const int tok0 = blockIdx.x * TPB;

    // --- Stage Eint: 1280 floats = 320 float4; 256 threads -> 2 each (64 idle 2nd) ---
    {
        const nfloat4* src = reinterpret_cast<const nfloat4*>(Eint);
        nfloat4*       dst = reinterpret_cast<nfloat4*>(&sEint[0][0]);
        dst[tid] = src[tid];                       // 0..255
        const int i2 = 256 + tid;
        if (i2 < (10 * D) / 4) dst[i2] = src[i2]; // 256..319
    }

    // --- Stage per-token metadata for all TPB tokens (coalesced) ---
    if (tid < TPB) {
        int tt = tok0 + tid; if (tt >= n) tt = n - 1;
        const int mod = mods[tt];
        const int fc  = first_chars[tt];
        sMod[tid]  = mod;
        sFidx[tid] = (mod == 0) ? (fc + 5) : (mod == 1) ? (fc * 2 + 5) : (52 + fc);
        sNd[tid]   = ndigits[tt];
        sVal[tid]  = vals[tt];
    }
    // digits: TPB*LM1 = 768 ints; 256 threads load 3 each, coalesced
    {
        const long lim = (long)n * LM1;
#pragma unroll
        for (int r = 0; r < (TPB * LM1) / 256; ++r) {
            const int i = tid + r * 256;
            long gi = (long)tok0 * LM1 + i;
            if (gi >= lim) gi = lim - 1;
            sDig[i] = digits[gi];
        }
    }

    // Position weights 1/(i+2)^kappa (uniform; tiny VALU).
    const int k = *kappa_p;
    float w[LM1];
#pragma unroll
    for (int i = 0; i < LM1; ++i) {
        float p = 1.0f;
        const float b = (float)(i + 2);
        for (int j = 0; j < k; ++j) p *= b;
        w[i] = 1.0f / p;
    }

    __syncthreads();

    const int q  = tid & 31;              // float4 slot within the D=128 row
    const int g  = tid >> 5;              // lane-group 0..7

#pragma unroll 2
    for (int c = 0; c < NCHUNK; ++c) {
        const int ltb = c * 32 + g * TPT; // first local token of this thread, this chunk

        // 4 independent E1 gathers (L2-resident table)
        nfloat4 base[TPT];
#pragma unroll
        for (int j = 0; j < TPT; ++j) {
            const int fidx = sFidx[ltb + j];   // LDS broadcast across lanes 0-31
            base[j] = *reinterpret_cast<const nfloat4*>(E1 + (size_t)fidx * D + q * 4);
        }

        // Accumulate digit embeddings from LDS
        nfloat4 acc[TPT];
#pragma unroll
        for (int j = 0; j < TPT; ++j) {
            const int lt  = ltb + j;
            const int mod = sMod[lt];
            if (mod == 2) {
                acc[j] = base[j] * sVal[lt];
            } else {
                acc[j] = base[j];
                const int nd = sNd[lt];
#pragma unroll
                for (int i = 0; i < LM1; ++i) {
                    if (i < nd) {          // uniform across the 32 lanes of a token
                        const int dg = sDig[lt * LM1 + i];
                        const nfloat4 e =
                            *reinterpret_cast<const nfloat4*>(&sEint[dg][q * 4]);
                        acc[j] += w[i] * e;
                    }
                }
            }
        }

        // Coalesced nontemporal stores: each j, lanes 0-31 cover one 512B row
#pragma unroll
        for (int j = 0; j < TPT; ++j) {
            const int tok = tok0 + ltb + j;
            if (tok < n) {
                __builtin_nontemporal_store(
                    acc[j],
                    reinterpret_cast<nfloat4*>(out + (size_t)tok * D + q * 4));
            }
        }
    }
}

extern "C" void kernel_launch(void* const* d_in, const int* in_sizes, int n_in,
                              void* d_out, int out_size, void* d_ws, size_t ws_size,
                              hipStream_t stream) {
    const int*   first_chars = (const int*)  d_in[0];
    const int*   digits      = (const int*)  d_in[1];
    const int*   ndigits     = (const int*)  d_in[2];
    const int*   mods        = (const int*)  d_in[3];
    const float* vals        = (const float*)d_in[4];
    const float* E1          = (const float*)d_in[5];
    const float* Eint        = (const float*)d_in[6];
    const int*   kappa       = (const int*)  d_in[7];
    float*       out         = (float*)d_out;

    const int n    = in_sizes[0];                 // tokens
    const int grid = (n + TPB - 1) / TPB;         // 2048 blocks at N=262144

    hier_emb_kernel<<<grid, 256, 0, stream>>>(
        first_chars, digits, ndigits, mods, vals, E1, Eint, kappa, out, n);
}